// Round 11
// baseline (36.629 us; speedup 1.0000x reference)
//
#include <hip/hip_runtime.h>

// Laplacian of MLP 3 -> 128(tanh) -> 64(tanh) -> 1 via Taylor jets,
// as 5 f16-MFMA GEMM families + VALU jet construction. Single fused
// kernel, LDS-staged weights, NO d_ws (poison-safe: reads only d_in).
//
// BLOCK=512 (8 waves), TILES=2: 512 blocks total; per-block setup (W2
// fragment pack) is paid once per 256 batch elements (vs once per 64 in
// round 8) -> aggregate setup work ~4x lower. Grid 512 = exactly 2
// resident blocks/CU at VGPR~88 (16 waves/CU), so no occupancy change.
//
// Math per batch element b, with h = tanh(x W1^T + b1), s = 1-h^2:
//   P0[j] = h[j]; Pd[j] = s[j]*W1[j][d]; Ps[j] = h s * (-2 sum_d W1[j][d]^2)
// z_f = P_f @ W2^T (5 families, K=128, 64 outputs), then
//   g0 = tanh(z0+b2), s2 = 1-g0^2
//   G2[k] = s2*zs[k] - 2 g0 s2 * (z1^2+z2^2+z3^2)[k]
//   out[b] = sum_k W3[k]*G2[k]     (b3 never enters the 2nd coefficient)
//
// MFMA: D = A*B, A = W2 tile [16k x 32j] (LDS, frag-ordered), B = jets
// [32j x 16b] (regs). Same assumed lane->k map on both operands => any HW
// k-permutation cancels. C/D: col=lane&15 (b), row=(lane>>4)*4+r (k).
//
// Transcendental folding: tanh(v) = 1 - 2/(exp2(C*v)+1), C = 2*log2(e).
// The C-scale is folded into the tables (C*b1 in s_w1p.w, C*b2 in s_b2c)
// and into per-tile x0c = C*x0 etc, so each tanh costs exp2+add+rcp+fma
// with no standalone scale-mul.
//
// NOTE: round-9's f16 pair-table construct (f32x4 LDS read + bit_cast +
// packed-h2 multiply) produced O(1)-wrong outputs; jet products stay in
// f32 (R8-verified form). Do not reintroduce without disasm evidence.

typedef _Float16 h2 __attribute__((ext_vector_type(2)));
typedef _Float16 h4 __attribute__((ext_vector_type(4)));
typedef _Float16 h8 __attribute__((ext_vector_type(8)));
typedef float f32x4 __attribute__((ext_vector_type(4)));

#define BLOCK 512
constexpr int DH1 = 128;
constexpr int DH2 = 64;
constexpr int TILES = 2;       // batch-tiles per block
constexpr float CTANH = 2.885390081777926814f;   // 2*log2(e)

__device__ __forceinline__ h2 pk(float a, float b) {
    auto r = __builtin_amdgcn_cvt_pkrtz(a, b);
    return __builtin_bit_cast(h2, r);
}

__device__ __forceinline__ h8 cat4(h2 a, h2 b, h2 c, h2 d) {
    h4 lo = __builtin_shufflevector(a, b, 0, 1, 2, 3);
    h4 hi = __builtin_shufflevector(c, d, 0, 1, 2, 3);
    return __builtin_shufflevector(lo, hi, 0, 1, 2, 3, 4, 5, 6, 7);
}

__global__ __launch_bounds__(BLOCK) void lap_fused(
        const float* __restrict__ x,
        const float* __restrict__ W1, const float* __restrict__ b1,
        const float* __restrict__ W2, const float* __restrict__ b2,
        const float* __restrict__ W3,
        float* __restrict__ out, int B, int ntiles)
{
    __shared__ float4 s_w1p[DH1];                     // {wx,wy,wz, C*b1}
    __shared__ float  s_wq2[DH1];                     // -2*sum_d W1[j][d]^2
    __shared__ __align__(16) _Float16 s_a[16][64][8]; // [(kk*4+m)][lane][i]
    __shared__ __align__(16) float s_b2c[DH2];        // C*b2
    __shared__ __align__(16) float s_w3[DH2];

    const int t    = threadIdx.x;
    const int lane = t & 63;
    const int wave = t >> 6;           // 0..7
    const int bcol = lane & 15;
    const int g    = lane >> 4;

    // ---- hoist both tiles' x loads (latency hides under setup) ----
    float xv[TILES][3];
    #pragma unroll
    for (int tile = 0; tile < TILES; ++tile) {
        const int tid  = blockIdx.x + tile * gridDim.x;
        const int braw = tid * 128 + wave * 16 + bcol;
        const int b    = (braw < B) ? braw : (B - 1);
        xv[tile][0] = x[b*3+0];
        xv[tile][1] = x[b*3+1];
        xv[tile][2] = x[b*3+2];
    }

    // ---- setup (once per block): pack W2 fragments + W1 tables ----
    #pragma unroll
    for (int u = 0; u < 2; ++u) {
        const int f   = u * 512 + t;      // fragment id 0..1023
        const int l   = f & 63;
        const int row = f >> 6;           // kk*4 + m
        const int m   = row & 3;
        const int kk  = row >> 2;
        const int k   = m * 16 + (l & 15);
        const int jr  = kk * 32 + (l >> 4) * 8;
        const float4 wlo = *reinterpret_cast<const float4*>(W2 + k * DH1 + jr);
        const float4 whi = *reinterpret_cast<const float4*>(W2 + k * DH1 + jr + 4);
        *reinterpret_cast<h8*>(&s_a[row][l][0]) =
            cat4(pk(wlo.x, wlo.y), pk(wlo.z, wlo.w),
                 pk(whi.x, whi.y), pk(whi.z, whi.w));
    }
    if (t < DH1) {
        const float wx = W1[t*3+0], wy = W1[t*3+1], wz = W1[t*3+2];
        s_w1p[t] = make_float4(wx, wy, wz, CTANH * b1[t]);
        s_wq2[t] = -2.0f * (wx*wx + wy*wy + wz*wz);
    }
    if (t < DH2) { s_b2c[t] = CTANH * b2[t]; s_w3[t] = W3[t]; }
    __syncthreads();

    #pragma unroll 1
    for (int tile = 0; tile < TILES; ++tile) {
        const int tid = blockIdx.x + tile * gridDim.x;   // batch-tile index
        if (tid >= ntiles) break;
        const int braw = tid * 128 + wave * 16 + bcol;

        const float x0c = xv[tile][0] * CTANH;
        const float x1c = xv[tile][1] * CTANH;
        const float x2c = xv[tile][2] * CTANH;

        f32x4 acc[5][4];
        #pragma unroll
        for (int f = 0; f < 5; ++f)
            #pragma unroll
            for (int m = 0; m < 4; ++m)
                acc[f][m] = (f32x4){0.f, 0.f, 0.f, 0.f};

        #pragma unroll
        for (int kk = 0; kk < 4; ++kk) {
            // ---- jets for this lane's 8 j's (4 independent pairs) ----
            h2 P0[4], P1[4], P2[4], P3[4], P4[4];
            #pragma unroll
            for (int ii = 0; ii < 4; ++ii) {
                const int j0 = kk*32 + g*8 + ii*2;
                const float4 wa = s_w1p[j0];
                const float4 wb = s_w1p[j0 + 1];
                const float  qa = s_wq2[j0];
                const float  qb = s_wq2[j0 + 1];

                // pre_scaled = C*(x.w + b1); tanh = 1 - 2*rcp(exp2(pre)+1)
                const float prea = fmaf(x0c, wa.x, fmaf(x1c, wa.y, fmaf(x2c, wa.z, wa.w)));
                const float ea   = __builtin_amdgcn_exp2f(prea);
                const float ra   = __builtin_amdgcn_rcpf(ea + 1.0f);
                const float ha   = fmaf(-2.0f, ra, 1.0f);
                const float sa   = fmaf(-ha, ha, 1.0f);

                const float preb = fmaf(x0c, wb.x, fmaf(x1c, wb.y, fmaf(x2c, wb.z, wb.w)));
                const float eb   = __builtin_amdgcn_exp2f(preb);
                const float rb   = __builtin_amdgcn_rcpf(eb + 1.0f);
                const float hb   = fmaf(-2.0f, rb, 1.0f);
                const float sb   = fmaf(-hb, hb, 1.0f);

                P0[ii] = pk(ha,          hb);
                P1[ii] = pk(sa * wa.x,   sb * wb.x);
                P2[ii] = pk(sa * wa.y,   sb * wb.y);
                P3[ii] = pk(sa * wa.z,   sb * wb.z);
                P4[ii] = pk((ha*sa)*qa,  (hb*sb)*qb);
            }
            const h8 F0 = cat4(P0[0], P0[1], P0[2], P0[3]);
            const h8 F1 = cat4(P1[0], P1[1], P1[2], P1[3]);
            const h8 F2 = cat4(P2[0], P2[1], P2[2], P2[3]);
            const h8 F3 = cat4(P3[0], P3[1], P3[2], P3[3]);
            const h8 F4 = cat4(P4[0], P4[1], P4[2], P4[3]);

            #pragma unroll
            for (int m = 0; m < 4; ++m) {
                const h8 fa = *reinterpret_cast<const h8*>(&s_a[kk*4 + m][lane][0]);
                acc[0][m] = __builtin_amdgcn_mfma_f32_16x16x32_f16(fa, F0, acc[0][m], 0, 0, 0);
                acc[1][m] = __builtin_amdgcn_mfma_f32_16x16x32_f16(fa, F1, acc[1][m], 0, 0, 0);
                acc[2][m] = __builtin_amdgcn_mfma_f32_16x16x32_f16(fa, F2, acc[2][m], 0, 0, 0);
                acc[3][m] = __builtin_amdgcn_mfma_f32_16x16x32_f16(fa, F3, acc[3][m], 0, 0, 0);
                acc[4][m] = __builtin_amdgcn_mfma_f32_16x16x32_f16(fa, F4, acc[4][m], 0, 0, 0);
            }
        }

        // ---- epilogue: lane holds k = m*16 + g*4 + r for its batch column ----
        float partial = 0.0f;
        #pragma unroll
        for (int m = 0; m < 4; ++m) {
            const int kb = m*16 + g*4;
            const f32x4 b2v = *reinterpret_cast<const f32x4*>(&s_b2c[kb]);
            const f32x4 w3v = *reinterpret_cast<const f32x4*>(&s_w3[kb]);
            #pragma unroll
            for (int r = 0; r < 4; ++r) {
                // g0 = tanh(z0 + b2) with C-scale folded: arg = C*acc + C*b2
                const float e0 = __builtin_amdgcn_exp2f(fmaf(CTANH, acc[0][m][r], b2v[r]));
                const float g0 = fmaf(-2.0f, __builtin_amdgcn_rcpf(e0 + 1.0f), 1.0f);
                const float s2 = fmaf(-g0, g0, 1.0f);
                const float qd = acc[1][m][r]*acc[1][m][r]
                               + acc[2][m][r]*acc[2][m][r]
                               + acc[3][m][r]*acc[3][m][r];
                const float G2 = s2 * fmaf(-2.0f * g0, qd, acc[4][m][r]);
                partial = fmaf(w3v[r], G2, partial);
            }
        }

        partial += __shfl_xor(partial, 16);
        partial += __shfl_xor(partial, 32);

        if (g == 0 && braw < B) out[braw] = partial;
    }
}

extern "C" void kernel_launch(void* const* d_in, const int* in_sizes, int n_in,
                              void* d_out, int out_size, void* d_ws, size_t ws_size,
                              hipStream_t stream) {
    const float* x  = (const float*)d_in[0];
    const float* W1 = (const float*)d_in[1];
    const float* b1 = (const float*)d_in[2];
    const float* W2 = (const float*)d_in[3];
    const float* b2 = (const float*)d_in[4];
    const float* W3 = (const float*)d_in[5];
    // d_in[6] = b3: does not enter the 2nd Taylor coefficient.
    float* out = (float*)d_out;

    const int B      = in_sizes[0] / 3;
    const int ntiles = (B + 127) / 128;              // 128 batch per block-tile
    const int grid   = (ntiles + TILES - 1) / TILES;
    lap_fused<<<grid, BLOCK, 0, stream>>>(x, W1, b1, W2, b2, W3, out, B, ntiles);
}

// Round 12
// 25.361 us; speedup vs baseline: 1.4443x; 1.4443x over previous
//
#include <hip/hip_runtime.h>

// Laplacian of MLP 3 -> 128(tanh) -> 64(tanh) -> 1 via Taylor jets,
// as 5 f16-MFMA GEMM families + VALU jet construction. Single fused
// kernel, LDS-staged weights, NO d_ws (poison-safe: reads only d_in).
// BLOCK=256, TILES=2, grid ~1024 (R10-verified shape: >=4 blocks/CU for
// fine-grained load balance; BLOCK=512/grid=512 regressed 41% in R11).
//
// Math per batch element b, with h = tanh(x W1^T + b1), s = 1-h^2:
//   P0[j] = h[j]; Pd[j] = s[j]*W1[j][d]; Ps[j] = h s * (-2 sum_d W1[j][d]^2)
// z_f = P_f @ W2^T (5 families, K=128, 64 outputs), then
//   g0 = tanh(z0+b2), s2 = 1-g0^2
//   G2[k] = s2*zs[k] - 2 g0 s2 * (z1^2+z2^2+z3^2)[k]
//   out[b] = sum_k W3[k]*G2[k]     (b3 never enters the 2nd coefficient)
//
// MFMA: D = A*B, A = W2 tile [16k x 32j] (LDS, frag-ordered), B = jets
// [32j x 16b] (regs). Same assumed lane->k map on both operands => any HW
// k-permutation cancels. C/D: col=lane&15 (b), row=(lane>>4)*4+r (k).
//
// Transcendental folding: tanh(v) = 1 - 2/(exp2(C*v)+1), C = 2*log2(e).
// C is folded into tables (C*b1, C*b2) and per-tile x*C, so each tanh is
// exp2+add+rcp+fma with no standalone scale-mul.
//
// NOTE: round-9's f16 pair-table construct (f32x4 LDS read + bit_cast +
// packed-h2 multiply) produced O(1)-wrong outputs; jet products stay in
// f32 (R8-verified form). Do not reintroduce without disasm evidence.

typedef _Float16 h2 __attribute__((ext_vector_type(2)));
typedef _Float16 h4 __attribute__((ext_vector_type(4)));
typedef _Float16 h8 __attribute__((ext_vector_type(8)));
typedef float f32x4 __attribute__((ext_vector_type(4)));

#define BLOCK 256
constexpr int DH1 = 128;
constexpr int DH2 = 64;
constexpr int TILES = 2;       // batch-tiles per block
constexpr float CTANH = 2.885390081777926814f;   // 2*log2(e)

__device__ __forceinline__ h2 pk(float a, float b) {
    auto r = __builtin_amdgcn_cvt_pkrtz(a, b);
    return __builtin_bit_cast(h2, r);
}

__device__ __forceinline__ h8 cat4(h2 a, h2 b, h2 c, h2 d) {
    h4 lo = __builtin_shufflevector(a, b, 0, 1, 2, 3);
    h4 hi = __builtin_shufflevector(c, d, 0, 1, 2, 3);
    return __builtin_shufflevector(lo, hi, 0, 1, 2, 3, 4, 5, 6, 7);
}

__global__ __launch_bounds__(BLOCK) void lap_fused(
        const float* __restrict__ x,
        const float* __restrict__ W1, const float* __restrict__ b1,
        const float* __restrict__ W2, const float* __restrict__ b2,
        const float* __restrict__ W3,
        float* __restrict__ out, int B, int ntiles)
{
    __shared__ float4 s_w1p[DH1];                     // {wx,wy,wz, C*b1}
    __shared__ float  s_wq2[DH1];                     // -2*sum_d W1[j][d]^2
    __shared__ __align__(16) _Float16 s_a[16][64][8]; // [(kk*4+m)][lane][i]
    __shared__ __align__(16) float s_b2c[DH2];        // C*b2
    __shared__ __align__(16) float s_w3[DH2];

    const int t    = threadIdx.x;
    const int lane = t & 63;
    const int wave = t >> 6;
    const int bcol = lane & 15;
    const int g    = lane >> 4;

    // ---- hoist both tiles' x loads (latency hides under setup pack) ----
    float xv[TILES][3];
    #pragma unroll
    for (int tile = 0; tile < TILES; ++tile) {
        const int tid  = blockIdx.x + tile * gridDim.x;
        const int braw = tid * 64 + wave * 16 + bcol;
        const int b    = (braw < B) ? braw : (B - 1);
        xv[tile][0] = x[b*3+0];
        xv[tile][1] = x[b*3+1];
        xv[tile][2] = x[b*3+2];
    }

    // ---- setup (once per block): pack W2 fragments + W1 tables ----
    #pragma unroll
    for (int u = 0; u < 4; ++u) {
        const int f   = u * 256 + t;      // fragment id 0..1023
        const int l   = f & 63;
        const int row = f >> 6;           // kk*4 + m
        const int m   = row & 3;
        const int kk  = row >> 2;
        const int k   = m * 16 + (l & 15);
        const int jr  = kk * 32 + (l >> 4) * 8;
        const float4 wlo = *reinterpret_cast<const float4*>(W2 + k * DH1 + jr);
        const float4 whi = *reinterpret_cast<const float4*>(W2 + k * DH1 + jr + 4);
        *reinterpret_cast<h8*>(&s_a[row][l][0]) =
            cat4(pk(wlo.x, wlo.y), pk(wlo.z, wlo.w),
                 pk(whi.x, whi.y), pk(whi.z, whi.w));
    }
    if (t < DH1) {
        const float wx = W1[t*3+0], wy = W1[t*3+1], wz = W1[t*3+2];
        s_w1p[t] = make_float4(wx, wy, wz, CTANH * b1[t]);
        s_wq2[t] = -2.0f * (wx*wx + wy*wy + wz*wz);
    }
    if (t < DH2) { s_b2c[t] = CTANH * b2[t]; s_w3[t] = W3[t]; }
    __syncthreads();

    #pragma unroll 1
    for (int tile = 0; tile < TILES; ++tile) {
        const int tid = blockIdx.x + tile * gridDim.x;   // batch-tile index
        if (tid >= ntiles) break;
        const int braw = tid * 64 + wave * 16 + bcol;

        const float x0c = xv[tile][0] * CTANH;
        const float x1c = xv[tile][1] * CTANH;
        const float x2c = xv[tile][2] * CTANH;

        f32x4 acc[5][4];
        #pragma unroll
        for (int f = 0; f < 5; ++f)
            #pragma unroll
            for (int m = 0; m < 4; ++m)
                acc[f][m] = (f32x4){0.f, 0.f, 0.f, 0.f};

        #pragma unroll
        for (int kk = 0; kk < 4; ++kk) {
            // ---- jets for this lane's 8 j's (4 independent pairs) ----
            h2 P0[4], P1[4], P2[4], P3[4], P4[4];
            #pragma unroll
            for (int ii = 0; ii < 4; ++ii) {
                const int j0 = kk*32 + g*8 + ii*2;
                const float4 wa = s_w1p[j0];
                const float4 wb = s_w1p[j0 + 1];
                const float  qa = s_wq2[j0];
                const float  qb = s_wq2[j0 + 1];

                // pre = C*(x.w1 + b1); tanh = 1 - 2*rcp(exp2(pre)+1)
                const float prea = fmaf(x0c, wa.x, fmaf(x1c, wa.y, fmaf(x2c, wa.z, wa.w)));
                const float ea   = __builtin_amdgcn_exp2f(prea);
                const float ra   = __builtin_amdgcn_rcpf(ea + 1.0f);
                const float ha   = fmaf(-2.0f, ra, 1.0f);
                const float sa   = fmaf(-ha, ha, 1.0f);

                const float preb = fmaf(x0c, wb.x, fmaf(x1c, wb.y, fmaf(x2c, wb.z, wb.w)));
                const float eb   = __builtin_amdgcn_exp2f(preb);
                const float rb   = __builtin_amdgcn_rcpf(eb + 1.0f);
                const float hb   = fmaf(-2.0f, rb, 1.0f);
                const float sb   = fmaf(-hb, hb, 1.0f);

                P0[ii] = pk(ha,          hb);
                P1[ii] = pk(sa * wa.x,   sb * wb.x);
                P2[ii] = pk(sa * wa.y,   sb * wb.y);
                P3[ii] = pk(sa * wa.z,   sb * wb.z);
                P4[ii] = pk((ha*sa)*qa,  (hb*sb)*qb);
            }
            const h8 F0 = cat4(P0[0], P0[1], P0[2], P0[3]);
            const h8 F1 = cat4(P1[0], P1[1], P1[2], P1[3]);
            const h8 F2 = cat4(P2[0], P2[1], P2[2], P2[3]);
            const h8 F3 = cat4(P3[0], P3[1], P3[2], P3[3]);
            const h8 F4 = cat4(P4[0], P4[1], P4[2], P4[3]);

            #pragma unroll
            for (int m = 0; m < 4; ++m) {
                const h8 fa = *reinterpret_cast<const h8*>(&s_a[kk*4 + m][lane][0]);
                acc[0][m] = __builtin_amdgcn_mfma_f32_16x16x32_f16(fa, F0, acc[0][m], 0, 0, 0);
                acc[1][m] = __builtin_amdgcn_mfma_f32_16x16x32_f16(fa, F1, acc[1][m], 0, 0, 0);
                acc[2][m] = __builtin_amdgcn_mfma_f32_16x16x32_f16(fa, F2, acc[2][m], 0, 0, 0);
                acc[3][m] = __builtin_amdgcn_mfma_f32_16x16x32_f16(fa, F3, acc[3][m], 0, 0, 0);
                acc[4][m] = __builtin_amdgcn_mfma_f32_16x16x32_f16(fa, F4, acc[4][m], 0, 0, 0);
            }
        }

        // ---- epilogue: lane holds k = m*16 + g*4 + r for its batch column ----
        float partial = 0.0f;
        #pragma unroll
        for (int m = 0; m < 4; ++m) {
            const int kb = m*16 + g*4;
            const f32x4 b2v = *reinterpret_cast<const f32x4*>(&s_b2c[kb]);
            const f32x4 w3v = *reinterpret_cast<const f32x4*>(&s_w3[kb]);
            #pragma unroll
            for (int r = 0; r < 4; ++r) {
                // g0 = tanh(z0 + b2): arg = C*acc + C*b2 (folded)
                const float e0 = __builtin_amdgcn_exp2f(fmaf(CTANH, acc[0][m][r], b2v[r]));
                const float g0 = fmaf(-2.0f, __builtin_amdgcn_rcpf(e0 + 1.0f), 1.0f);
                const float s2 = fmaf(-g0, g0, 1.0f);
                const float qd = acc[1][m][r]*acc[1][m][r]
                               + acc[2][m][r]*acc[2][m][r]
                               + acc[3][m][r]*acc[3][m][r];
                const float G2 = s2 * fmaf(-2.0f * g0, qd, acc[4][m][r]);
                partial = fmaf(w3v[r], G2, partial);
            }
        }

        partial += __shfl_xor(partial, 16);
        partial += __shfl_xor(partial, 32);

        if (g == 0 && braw < B) out[braw] = partial;
    }
}

extern "C" void kernel_launch(void* const* d_in, const int* in_sizes, int n_in,
                              void* d_out, int out_size, void* d_ws, size_t ws_size,
                              hipStream_t stream) {
    const float* x  = (const float*)d_in[0];
    const float* W1 = (const float*)d_in[1];
    const float* b1 = (const float*)d_in[2];
    const float* W2 = (const float*)d_in[3];
    const float* b2 = (const float*)d_in[4];
    const float* W3 = (const float*)d_in[5];
    // d_in[6] = b3: does not enter the 2nd Taylor coefficient.
    float* out = (float*)d_out;

    const int B      = in_sizes[0] / 3;
    const int ntiles = (B + 63) / 64;                // 64 batch per tile
    const int grid   = (ntiles + TILES - 1) / TILES; // ~1024 blocks
    lap_fused<<<grid, BLOCK, 0, stream>>>(x, W1, b1, W2, b2, W3, out, B, ntiles);
}